// Round 2
// baseline (219.164 us; speedup 1.0000x reference)
//
#include <hip/hip_runtime.h>
#include <math.h>

#define N_NODES 20000
#define N_EDGES 320000
#define IN_F 256
#define OUT_F 64
#define HEADS 4
#define NCOL 256            // HEADS*OUT_F
#define LRELU_ALPHA 0.1f
#define ELL_CAP 64          // max degree capacity; P(overflow) < 1e-13

#define SCAT_BLOCKS 640
#define SCAT_THREADS (SCAT_BLOCKS * 256)   // 163840: each thread <= 2 edges

#define WRES_BLOCKS 128                    // per direction; 256 total = 1/CU
#define LDS_STRIDE 264                     // shorts per row: 256 + 8 pad (16B-aligned rows)

#define AGG_BLOCKS 2048                    // 8 slices x 256 index-blocks

typedef __attribute__((ext_vector_type(8))) short short8;
typedef __attribute__((ext_vector_type(4))) float floatx4;

__device__ __forceinline__ float lrelu(float x) {
    return x > 0.f ? x : LRELU_ALPHA * x;
}
__device__ __forceinline__ unsigned short f2bf(float f) {   // RNE f32->bf16
    unsigned int u = __float_as_uint(f);
    u = (u + 0x7FFF + ((u >> 16) & 1)) >> 16;
    return (unsigned short)u;
}
__device__ __forceinline__ float bf2f(unsigned short u) {
    return __uint_as_float(((unsigned int)u) << 16);
}

// ---------------------------------------------------------------------------
// prep_w (64 blocks x 256): W[h][k][j] f32 -> Wb[c][k] bf16 (c=h*64+j,
// k contiguous) AND zero the 2*N_NODES ELL counters.
// ---------------------------------------------------------------------------
__global__ __launch_bounds__(256) void prep_w_kernel(
    const float* __restrict__ Ws, const float* __restrict__ Wt,
    unsigned short* __restrict__ Wsb, unsigned short* __restrict__ Wtb,
    int* __restrict__ cnt)   // cnt_t followed by cnt_s
{
    const int gid = blockIdx.x * 256 + threadIdx.x;   // [0, 16384)

    for (int i = gid; i < 2 * N_NODES; i += 16384) cnt[i] = 0;

    const int mat = gid >> 13;
    const int r   = gid & 8191;
    const int kc  = r >> 8;          // 0..31 (k-octet)
    const int c   = r & 255;
    const float* W    = mat ? Wt : Ws;
    unsigned short* O = mat ? Wtb : Wsb;
    const int h = c >> 6, j = c & 63;
    const int k0 = kc * 8;
    unsigned short v[8] __attribute__((aligned(16)));
#pragma unroll
    for (int i = 0; i < 8; ++i)
        v[i] = f2bf(W[(size_t)h * (IN_F * OUT_F) + (size_t)(k0 + i) * OUT_F + j]);
    *(uint4*)(O + (size_t)c * IN_F + k0) = *(const uint4*)v;
}

// ---------------------------------------------------------------------------
// scatter: standalone ELL build (ushort entries).
// ---------------------------------------------------------------------------
__global__ __launch_bounds__(256) void scatter_kernel(
    const int* __restrict__ src, const int* __restrict__ tgt,
    int* __restrict__ cnt_t, int* __restrict__ cnt_s,
    unsigned short* __restrict__ elist_t, unsigned short* __restrict__ elist_s)
{
    const int e0 = blockIdx.x * 256 + threadIdx.x;       // always < N_EDGES
    const int e1 = e0 + SCAT_THREADS;
    const bool h1 = e1 < N_EDGES;

    int s0 = src[e0], t0 = tgt[e0];
    int s1 = 0, t1 = 0;
    if (h1) { s1 = src[e1]; t1 = tgt[e1]; }

    int p0 = atomicAdd(&cnt_t[t0], 1);
    int q0 = atomicAdd(&cnt_s[s0], 1);
    int p1 = 0, q1 = 0;
    if (h1) {
        p1 = atomicAdd(&cnt_t[t1], 1);
        q1 = atomicAdd(&cnt_s[s1], 1);
    }

    if (p0 < ELL_CAP) elist_t[t0 * ELL_CAP + p0] = (unsigned short)s0;
    if (q0 < ELL_CAP) elist_s[s0 * ELL_CAP + q0] = (unsigned short)t0;
    if (h1) {
        if (p1 < ELL_CAP) elist_t[t1 * ELL_CAP + p1] = (unsigned short)s1;
        if (q1 < ELL_CAP) elist_s[s1 * ELL_CAP + q1] = (unsigned short)t1;
    }
}

// ---------------------------------------------------------------------------
// gemm_wres: W-resident GEMM + fused dots, 1024-thread blocks.
// grid (128, 2) x 1024. Whole Wb staged to LDS once (135 KB -> 1 block/CU,
// 16 waves = 4/SIMD). Each wave owns one 16-row group (2048 slots >= 1250
// groups). A loads split in two 8xfloat4 halves; second half issued before
// the first half's 64 MFMAs so its HBM latency hides under compute.
// ---------------------------------------------------------------------------
__global__ __launch_bounds__(1024, 4) void gemm_wres_kernel(
    const float* __restrict__ A0, const unsigned short* __restrict__ Wb0,
    const float* __restrict__ A1, const unsigned short* __restrict__ Wb1,
    unsigned short* __restrict__ C0, unsigned short* __restrict__ C1,
    const float* __restrict__ a1, const float* __restrict__ a2,
    float* __restrict__ ss1, float* __restrict__ ss2,
    float* __restrict__ tt1, float* __restrict__ tt2)
{
    const int tid = threadIdx.x;
    const float* A           = (blockIdx.y == 0) ? A0 : A1;
    const unsigned short* Wb = (blockIdx.y == 0) ? Wb0 : Wb1;
    unsigned short* C        = (blockIdx.y == 0) ? C0 : C1;

    __shared__ __align__(16) unsigned short Bl[256][LDS_STRIDE];  // 135,168 B

    // ---- stage full Wb once ----
    for (int i = tid; i < 8192; i += 1024) {
        const int n  = i >> 5;            // col 0..255
        const int kc = (i & 31) << 3;     // k-offset in shorts
        *(uint4*)&Bl[n][kc] = *(const uint4*)(Wb + (size_t)n * IN_F + kc);
    }
    __syncthreads();

    const int lane = tid & 63;
    const int w    = tid >> 6;            // wave 0..15
    const int quad = lane >> 4;
    const int l15  = lane & 15;
    const int g    = blockIdx.x * 16 + w; // group id, 0..2047

    if (g >= 1250) return;

    const float* arow = A + (size_t)(g * 16 + l15) * IN_F + quad * 8;

    // half 1: kk = 0..3
    float4 ua[8];
#pragma unroll
    for (int kk = 0; kk < 4; ++kk) {
        ua[2 * kk]     = *(const float4*)(arow + kk * 32);
        ua[2 * kk + 1] = *(const float4*)(arow + kk * 32 + 4);
    }
    short8 af[4];
#pragma unroll
    for (int kk = 0; kk < 4; ++kk) {
        short8 t;
        t[0] = (short)f2bf(ua[2 * kk].x);     t[1] = (short)f2bf(ua[2 * kk].y);
        t[2] = (short)f2bf(ua[2 * kk].z);     t[3] = (short)f2bf(ua[2 * kk].w);
        t[4] = (short)f2bf(ua[2 * kk + 1].x); t[5] = (short)f2bf(ua[2 * kk + 1].y);
        t[6] = (short)f2bf(ua[2 * kk + 1].z); t[7] = (short)f2bf(ua[2 * kk + 1].w);
        af[kk] = t;
    }

    // issue half-2 loads now; they fly under the half-1 MFMA cluster
    float4 ub[8];
#pragma unroll
    for (int kk = 0; kk < 4; ++kk) {
        ub[2 * kk]     = *(const float4*)(arow + (kk + 4) * 32);
        ub[2 * kk + 1] = *(const float4*)(arow + (kk + 4) * 32 + 4);
    }

    floatx4 acc[16];
#pragma unroll
    for (int c = 0; c < 16; ++c) acc[c] = (floatx4){0.f, 0.f, 0.f, 0.f};

#pragma unroll
    for (int kk = 0; kk < 4; ++kk) {
#pragma unroll
        for (int c = 0; c < 16; ++c) {
            short8 bfrag = *(const short8*)&Bl[c * 16 + l15][kk * 32 + quad * 8];
            acc[c] = __builtin_amdgcn_mfma_f32_16x16x32_bf16(af[kk], bfrag, acc[c], 0, 0, 0);
        }
    }

#pragma unroll
    for (int kk = 0; kk < 4; ++kk) {
        short8 t;
        t[0] = (short)f2bf(ub[2 * kk].x);     t[1] = (short)f2bf(ub[2 * kk].y);
        t[2] = (short)f2bf(ub[2 * kk].z);     t[3] = (short)f2bf(ub[2 * kk].w);
        t[4] = (short)f2bf(ub[2 * kk + 1].x); t[5] = (short)f2bf(ub[2 * kk + 1].y);
        t[6] = (short)f2bf(ub[2 * kk + 1].z); t[7] = (short)f2bf(ub[2 * kk + 1].w);
        af[kk] = t;
    }
#pragma unroll
    for (int kk = 0; kk < 4; ++kk) {
#pragma unroll
        for (int c = 0; c < 16; ++c) {
            short8 bfrag = *(const short8*)&Bl[c * 16 + l15][(kk + 4) * 32 + quad * 8];
            acc[c] = __builtin_amdgcn_mfma_f32_16x16x32_bf16(af[kk], bfrag, acc[c], 0, 0, 0);
        }
    }

    // ---- C write (bf16) ----
#pragma unroll
    for (int c = 0; c < 16; ++c) {
        const int col = c * 16 + l15;
#pragma unroll
        for (int r = 0; r < 4; ++r) {
            const int m = g * 16 + quad * 4 + r;
            C[(size_t)m * NCOL + col] = f2bf(acc[c][r]);
        }
    }

    // ---- fused dots ----
    const int off_aj = (blockIdx.y == 0) ? 0 : 64;
    float* o1 = (blockIdx.y == 0) ? ss1 : tt1;
    float* o2 = (blockIdx.y == 0) ? ss2 : tt2;

    float p1[4][4] = {{0.f,0.f,0.f,0.f},{0.f,0.f,0.f,0.f},{0.f,0.f,0.f,0.f},{0.f,0.f,0.f,0.f}};
    float p2[4][4] = {{0.f,0.f,0.f,0.f},{0.f,0.f,0.f,0.f},{0.f,0.f,0.f,0.f},{0.f,0.f,0.f,0.f}};
#pragma unroll
    for (int c = 0; c < 16; ++c) {
        const int hh = c >> 2;
        const int jj = (c & 3) * 16 + l15;
        const float w1 = a1[hh * 128 + off_aj + jj];
        const float w2 = a2[hh * 128 + off_aj + jj];
#pragma unroll
        for (int r = 0; r < 4; ++r) {
            p1[hh][r] += acc[c][r] * w1;
            p2[hh][r] += acc[c][r] * w2;
        }
    }
#pragma unroll
    for (int m = 1; m < 16; m <<= 1) {
#pragma unroll
        for (int hh = 0; hh < 4; ++hh)
#pragma unroll
            for (int r = 0; r < 4; ++r) {
                p1[hh][r] += __shfl_xor(p1[hh][r], m, 64);
                p2[hh][r] += __shfl_xor(p2[hh][r], m, 64);
            }
    }
    if (l15 == 0) {
#pragma unroll
        for (int r = 0; r < 4; ++r) {
            const int m = g * 16 + quad * 4 + r;
#pragma unroll
            for (int hh = 0; hh < 4; ++hh) {
                o1[m * HEADS + hh] = p1[hh][r];
                o2[m * HEADS + hh] = p2[hh][r];
            }
        }
    }
}

// ---------------------------------------------------------------------------
// agg: XCD-sliced by (dir, head). slice = blockIdx.x & 7 (= XCD under
// round-robin dispatch): each XCD's L2 holds only ONE 64-col table stripe
// (2.56 MB) + elist + esc -> gathers become L2 hits instead of cross-XCD
// HBM replication. Within a wave: 16 lanes x ushort4 cover one edge's
// 64-col stripe; 4 edges in flight (quads); 2-deep unroll for dual
// dependent-load chains. Reduction over quads via 2 shfl_xor steps.
// ---------------------------------------------------------------------------
__global__ __launch_bounds__(256) void agg_kernel(
    const int* __restrict__ cnt_t, const unsigned short* __restrict__ elist_t,
    const int* __restrict__ cnt_s, const unsigned short* __restrict__ elist_s,
    const float* __restrict__ ss1, const float* __restrict__ ss2,
    const float* __restrict__ tt1, const float* __restrict__ tt2,
    const unsigned short* __restrict__ s_bf, const unsigned short* __restrict__ t_bf,
    float* __restrict__ h_st, float* __restrict__ h_ts)
{
    const int b     = blockIdx.x;
    const int slice = b & 7;            // = XCD id (round-robin dispatch)
    const int dir   = slice >> 2;
    const int h     = slice & 3;
    const int idx   = b >> 3;           // 0..255 within slice
    const int wave  = threadIdx.x >> 6;
    const int lane  = threadIdx.x & 63;
    const int quad  = lane >> 4;        // edge sub-slot 0..3
    const int l15   = lane & 15;
    const int coff  = h * 64 + l15 * 4; // column within table row

    const int*            cnt   = dir ? cnt_s   : cnt_t;
    const unsigned short* list  = dir ? elist_s : elist_t;
    const unsigned short* table = dir ? t_bf    : s_bf;
    const float*          nsc   = dir ? ss2     : tt1;
    const float*          esc   = dir ? tt2     : ss1;
    float*                outp  = dir ? h_st    : h_ts;

    const int nstart = (idx * N_NODES) >> 8;
    const int nend   = ((idx + 1) * N_NODES) >> 8;

    for (int n = nstart + wave; n < nend; n += 4) {
        const float base = nsc[n * HEADS + h];
        int deg = cnt[n];
        if (deg > ELL_CAP) deg = ELL_CAP;
        const unsigned short* lp = list + n * ELL_CAP;

        float4 acc = make_float4(0.f, 0.f, 0.f, 0.f);
        float den = 0.f;

        int p = quad;
        for (; p + 4 < deg; p += 8) {          // two edges per quad-slot
            int m0 = lp[p], m1 = lp[p + 4];
            float e0 = esc[m0 * HEADS + h];
            float e1 = esc[m1 * HEADS + h];
            ushort4 r0 = *(const ushort4*)(table + (size_t)m0 * NCOL + coff);
            ushort4 r1 = *(const ushort4*)(table + (size_t)m1 * NCOL + coff);
            float w0 = __expf(lrelu(e0 + base));
            float w1 = __expf(lrelu(e1 + base));
            den += w0 + w1;
            acc.x += w0 * bf2f(r0.x) + w1 * bf2f(r1.x);
            acc.y += w0 * bf2f(r0.y) + w1 * bf2f(r1.y);
            acc.z += w0 * bf2f(r0.z) + w1 * bf2f(r1.z);
            acc.w += w0 * bf2f(r0.w) + w1 * bf2f(r1.w);
        }
        if (p < deg) {
            int m0 = lp[p];
            float w0 = __expf(lrelu(esc[m0 * HEADS + h] + base));
            ushort4 r0 = *(const ushort4*)(table + (size_t)m0 * NCOL + coff);
            den += w0;
            acc.x += w0 * bf2f(r0.x);
            acc.y += w0 * bf2f(r0.y);
            acc.z += w0 * bf2f(r0.z);
            acc.w += w0 * bf2f(r0.w);
        }

        // reduce over the 4 quads (lanes l15, l15+16, l15+32, l15+48)
#pragma unroll
        for (int msk = 16; msk < 64; msk <<= 1) {
            den   += __shfl_xor(den,   msk, 64);
            acc.x += __shfl_xor(acc.x, msk, 64);
            acc.y += __shfl_xor(acc.y, msk, 64);
            acc.z += __shfl_xor(acc.z, msk, 64);
            acc.w += __shfl_xor(acc.w, msk, 64);
        }

        if (quad == 0) {
            if (den == 0.f) den = 1.f;
            float inv = 1.f / den;
            float4 r;
            r.x = acc.x * inv; r.y = acc.y * inv;
            r.z = acc.z * inv; r.w = acc.w * inv;
            r.x = (r.x > 0.f) ? r.x : expm1f(r.x);
            r.y = (r.y > 0.f) ? r.y : expm1f(r.y);
            r.z = (r.z > 0.f) ? r.z : expm1f(r.z);
            r.w = (r.w > 0.f) ? r.w : expm1f(r.w);
            *(float4*)(outp + (size_t)n * NCOL + coff) = r;
        }
    }
}

extern "C" void kernel_launch(void* const* d_in, const int* in_sizes, int n_in,
                              void* d_out, int out_size, void* d_ws, size_t ws_size,
                              hipStream_t stream)
{
    const float* input1 = (const float*)d_in[0];
    const float* input2 = (const float*)d_in[1];
    const float* Ws     = (const float*)d_in[2];
    const float* Wt     = (const float*)d_in[3];
    const float* a1     = (const float*)d_in[4];
    const float* a2     = (const float*)d_in[5];
    const int*   tgt    = (const int*)d_in[6];   // tgt_idx precedes src_idx
    const int*   src    = (const int*)d_in[7];

    float* out  = (float*)d_out;
    float* h_st = out;                            // [N, 256]
    float* h_ts = out + (size_t)N_NODES * NCOL;   // [N, 256]

    // workspace layout (~27.3 MB)
    unsigned short* s_bf = (unsigned short*)d_ws;             // 5,120,000 bf16
    unsigned short* t_bf = s_bf + (size_t)N_NODES * NCOL;     // 5,120,000 bf16
    unsigned short* Wsb  = t_bf + (size_t)N_NODES * NCOL;     // 65,536 bf16
    unsigned short* Wtb  = Wsb + 256 * 256;                   // 65,536 bf16
    float* ss1  = (float*)(Wtb + 256 * 256);                  // 80,000 f each
    float* ss2  = ss1 + N_NODES * HEADS;
    float* tt1  = ss2 + N_NODES * HEADS;
    float* tt2  = tt1 + N_NODES * HEADS;
    int*   cnt_t = (int*)(tt2 + N_NODES * HEADS);             // 20000
    int*   cnt_s = cnt_t + N_NODES;                           // 20000
    unsigned short* elist_t = (unsigned short*)(cnt_s + N_NODES);   // 20000*64 us
    unsigned short* elist_s = elist_t + (size_t)N_NODES * ELL_CAP;  // 20000*64 us

    // dispatch 1: W convert + counter zeroing
    prep_w_kernel<<<64, 256, 0, stream>>>(Ws, Wt, Wsb, Wtb, cnt_t);

    // dispatch 2: standalone ELL scatter
    scatter_kernel<<<SCAT_BLOCKS, 256, 0, stream>>>(src, tgt, cnt_t, cnt_s,
                                                    elist_t, elist_s);

    // dispatch 3: W-resident GEMM + fused dots (1024-thread blocks)
    dim3 ggrid(WRES_BLOCKS, 2);
    gemm_wres_kernel<<<ggrid, 1024, 0, stream>>>(input1, Wsb, input2, Wtb,
                                                 s_bf, t_bf, a1, a2,
                                                 ss1, ss2, tt1, tt2);

    // dispatch 4: XCD-sliced aggregation
    agg_kernel<<<AGG_BLOCKS, 256, 0, stream>>>(cnt_t, elist_t, cnt_s, elist_s,
                                               ss1, ss2, tt1, tt2, s_bf, t_bf, h_st, h_ts);
}

// Round 3
// 205.537 us; speedup vs baseline: 1.0663x; 1.0663x over previous
//
#include <hip/hip_runtime.h>
#include <math.h>

#define N_NODES 20000
#define N_EDGES 320000
#define IN_F 256
#define OUT_F 64
#define HEADS 4
#define NCOL 256            // HEADS*OUT_F
#define LRELU_ALPHA 0.1f
#define ELL_CAP 64          // max degree capacity; P(overflow) < 1e-13

#define SCAT_BLOCKS 1250                   // 1 edge per thread

#define GEMM_GB 157                        // ceil(1250 row-groups / 8 waves)
#define AGG_BLOCKS 2048                    // 8 (dir,head) slices x 256 node-blocks

typedef __attribute__((ext_vector_type(8))) short short8;
typedef __attribute__((ext_vector_type(4))) float floatx4;

__device__ __forceinline__ float lrelu(float x) {
    return x > 0.f ? x : LRELU_ALPHA * x;
}
__device__ __forceinline__ unsigned short f2bf(float f) {   // RNE f32->bf16
    unsigned int u = __float_as_uint(f);
    u = (u + 0x7FFF + ((u >> 16) & 1)) >> 16;
    return (unsigned short)u;
}
__device__ __forceinline__ float bf2f(unsigned short u) {
    return __uint_as_float(((unsigned int)u) << 16);
}

// ---------------------------------------------------------------------------
// prep_w (64 blocks x 256): W[h][k][j] f32 -> Wb[c][k] bf16 (c=h*64+j,
// k contiguous) AND zero the 2*N_NODES ELL counters.
// ---------------------------------------------------------------------------
__global__ __launch_bounds__(256) void prep_w_kernel(
    const float* __restrict__ Ws, const float* __restrict__ Wt,
    unsigned short* __restrict__ Wsb, unsigned short* __restrict__ Wtb,
    int* __restrict__ cnt)   // cnt_t followed by cnt_s
{
    const int gid = blockIdx.x * 256 + threadIdx.x;   // [0, 16384)

    for (int i = gid; i < 2 * N_NODES; i += 16384) cnt[i] = 0;

    const int mat = gid >> 13;
    const int r   = gid & 8191;
    const int kc  = r >> 8;          // 0..31 (k-octet)
    const int c   = r & 255;
    const float* W    = mat ? Wt : Ws;
    unsigned short* O = mat ? Wtb : Wsb;
    const int h = c >> 6, j = c & 63;
    const int k0 = kc * 8;
    unsigned short v[8] __attribute__((aligned(16)));
#pragma unroll
    for (int i = 0; i < 8; ++i)
        v[i] = f2bf(W[(size_t)h * (IN_F * OUT_F) + (size_t)(k0 + i) * OUT_F + j]);
    *(uint4*)(O + (size_t)c * IN_F + k0) = *(const uint4*)v;
}

// ---------------------------------------------------------------------------
// scatter: standalone ELL build (ushort entries). 1250 blocks x 256 =
// exactly one edge per thread -> max outstanding atomic parallelism.
// ---------------------------------------------------------------------------
__global__ __launch_bounds__(256) void scatter_kernel(
    const int* __restrict__ src, const int* __restrict__ tgt,
    int* __restrict__ cnt_t, int* __restrict__ cnt_s,
    unsigned short* __restrict__ elist_t, unsigned short* __restrict__ elist_s)
{
    const int e = blockIdx.x * 256 + threadIdx.x;    // always < N_EDGES
    const int s = src[e], t = tgt[e];
    const int p = atomicAdd(&cnt_t[t], 1);
    const int q = atomicAdd(&cnt_s[s], 1);
    if (p < ELL_CAP) elist_t[t * ELL_CAP + p] = (unsigned short)s;
    if (q < ELL_CAP) elist_s[s * ELL_CAP + q] = (unsigned short)t;
}

// ---------------------------------------------------------------------------
// gemm_wres: half-W-resident GEMM + fused dots.
// grid (157*2, 2) x 512. Each block stages ONE 128-col half of Wb (2 whole
// heads) into 66 KB LDS -> 2 blocks/CU, 16 waves/CU (4/SIMD). Each wave owns
// one 16-row group: A row loaded in two 8xfloat4 batches (2nd issued before
// the 1st MFMA cluster), 64 MFMAs, bf16 C write + fused a1/a2 dots for the
// 2 heads this half covers. Peak ~100 VGPR, no spill at the 128 cap.
// ---------------------------------------------------------------------------
__global__ __launch_bounds__(512, 4) void gemm_wres_kernel(
    const float* __restrict__ A0, const unsigned short* __restrict__ Wb0,
    const float* __restrict__ A1, const unsigned short* __restrict__ Wb1,
    unsigned short* __restrict__ C0, unsigned short* __restrict__ C1,
    const float* __restrict__ a1, const float* __restrict__ a2,
    float* __restrict__ ss1, float* __restrict__ ss2,
    float* __restrict__ tt1, float* __restrict__ tt2)
{
    const int tid  = threadIdx.x;
    const int half = blockIdx.x & 1;
    const int gb   = blockIdx.x >> 1;     // 0..156
    const float* A           = (blockIdx.y == 0) ? A0 : A1;
    const unsigned short* Wb = (blockIdx.y == 0) ? Wb0 : Wb1;
    unsigned short* C        = (blockIdx.y == 0) ? C0 : C1;

    __shared__ __align__(16) unsigned short Bl[128][264];   // 67,584 B

    // ---- stage this half's 128 cols: 4096 uint4, 8 per thread ----
    for (int i = tid; i < 4096; i += 512) {
        const int n  = i >> 5;            // 0..127
        const int kc = (i & 31) << 3;     // k-offset in shorts
        *(uint4*)&Bl[n][kc] = *(const uint4*)(Wb + (size_t)(half * 128 + n) * IN_F + kc);
    }
    __syncthreads();

    const int lane = tid & 63;
    const int w    = tid >> 6;            // wave 0..7
    const int quad = lane >> 4;
    const int l15  = lane & 15;
    const int g    = gb * 8 + w;          // row group 0..1255
    if (g >= 1250) return;

    const float* arow = A + (size_t)(g * 16 + l15) * IN_F + quad * 8;

    // batch 1: kk = 0..3
    float4 ua[8];
#pragma unroll
    for (int kk = 0; kk < 4; ++kk) {
        ua[2 * kk]     = *(const float4*)(arow + kk * 32);
        ua[2 * kk + 1] = *(const float4*)(arow + kk * 32 + 4);
    }
    short8 af[4];
#pragma unroll
    for (int kk = 0; kk < 4; ++kk) {
        short8 t;
        t[0] = (short)f2bf(ua[2 * kk].x);     t[1] = (short)f2bf(ua[2 * kk].y);
        t[2] = (short)f2bf(ua[2 * kk].z);     t[3] = (short)f2bf(ua[2 * kk].w);
        t[4] = (short)f2bf(ua[2 * kk + 1].x); t[5] = (short)f2bf(ua[2 * kk + 1].y);
        t[6] = (short)f2bf(ua[2 * kk + 1].z); t[7] = (short)f2bf(ua[2 * kk + 1].w);
        af[kk] = t;
    }

    // batch 2 loads fly under batch-1 MFMAs
    float4 ub[8];
#pragma unroll
    for (int kk = 0; kk < 4; ++kk) {
        ub[2 * kk]     = *(const float4*)(arow + (kk + 4) * 32);
        ub[2 * kk + 1] = *(const float4*)(arow + (kk + 4) * 32 + 4);
    }

    floatx4 acc[8];
#pragma unroll
    for (int c = 0; c < 8; ++c) acc[c] = (floatx4){0.f, 0.f, 0.f, 0.f};

#pragma unroll
    for (int kk = 0; kk < 4; ++kk) {
#pragma unroll
        for (int c = 0; c < 8; ++c) {
            short8 bfrag = *(const short8*)&Bl[c * 16 + l15][kk * 32 + quad * 8];
            acc[c] = __builtin_amdgcn_mfma_f32_16x16x32_bf16(af[kk], bfrag, acc[c], 0, 0, 0);
        }
    }

#pragma unroll
    for (int kk = 0; kk < 4; ++kk) {
        short8 t;
        t[0] = (short)f2bf(ub[2 * kk].x);     t[1] = (short)f2bf(ub[2 * kk].y);
        t[2] = (short)f2bf(ub[2 * kk].z);     t[3] = (short)f2bf(ub[2 * kk].w);
        t[4] = (short)f2bf(ub[2 * kk + 1].x); t[5] = (short)f2bf(ub[2 * kk + 1].y);
        t[6] = (short)f2bf(ub[2 * kk + 1].z); t[7] = (short)f2bf(ub[2 * kk + 1].w);
        af[kk] = t;
    }
#pragma unroll
    for (int kk = 0; kk < 4; ++kk) {
#pragma unroll
        for (int c = 0; c < 8; ++c) {
            short8 bfrag = *(const short8*)&Bl[c * 16 + l15][(kk + 4) * 32 + quad * 8];
            acc[c] = __builtin_amdgcn_mfma_f32_16x16x32_bf16(af[kk], bfrag, acc[c], 0, 0, 0);
        }
    }

    // ---- C write (bf16) ----
#pragma unroll
    for (int c = 0; c < 8; ++c) {
        const int col = half * 128 + c * 16 + l15;
#pragma unroll
        for (int r = 0; r < 4; ++r) {
            const int m = g * 16 + quad * 4 + r;
            C[(size_t)m * NCOL + col] = f2bf(acc[c][r]);
        }
    }

    // ---- fused dots for the 2 heads in this half ----
    const int off_aj = (blockIdx.y == 0) ? 0 : 64;
    float* o1 = (blockIdx.y == 0) ? ss1 : tt1;
    float* o2 = (blockIdx.y == 0) ? ss2 : tt2;

    float p1[2][4] = {{0.f,0.f,0.f,0.f},{0.f,0.f,0.f,0.f}};
    float p2[2][4] = {{0.f,0.f,0.f,0.f},{0.f,0.f,0.f,0.f}};
#pragma unroll
    for (int c = 0; c < 8; ++c) {
        const int hl = c >> 2;                       // local head 0..1
        const int hh = half * 2 + hl;
        const int jj = (c & 3) * 16 + l15;
        const float w1 = a1[hh * 128 + off_aj + jj];
        const float w2 = a2[hh * 128 + off_aj + jj];
#pragma unroll
        for (int r = 0; r < 4; ++r) {
            p1[hl][r] += acc[c][r] * w1;
            p2[hl][r] += acc[c][r] * w2;
        }
    }
#pragma unroll
    for (int m = 1; m < 16; m <<= 1) {
#pragma unroll
        for (int hl = 0; hl < 2; ++hl)
#pragma unroll
            for (int r = 0; r < 4; ++r) {
                p1[hl][r] += __shfl_xor(p1[hl][r], m, 64);
                p2[hl][r] += __shfl_xor(p2[hl][r], m, 64);
            }
    }
    if (l15 == 0) {
#pragma unroll
        for (int r = 0; r < 4; ++r) {
            const int m = g * 16 + quad * 4 + r;
#pragma unroll
            for (int hl = 0; hl < 2; ++hl) {
                const int hh = half * 2 + hl;
                o1[m * HEADS + hh] = p1[hl][r];
                o2[m * HEADS + hh] = p2[hl][r];
            }
        }
    }
}

// ---------------------------------------------------------------------------
// agg: (dir,head) XCD-sliced (slice = blockIdx.x & 7 -> round-robin XCD;
// each XCD's L2 holds one 2.56 MB table stripe). QUAD-PER-NODE: each 16-lane
// quad owns one node end-to-end -- each lane accumulates its own 4 columns
// over all edges, NO cross-lane reduction, direct float4 write. 4-edge
// unroll -> 16 independent gather chains per wave. 2048 blocks = 8/CU =
// 32 waves/CU.
// ---------------------------------------------------------------------------
__global__ __launch_bounds__(256) void agg_kernel(
    const int* __restrict__ cnt_t, const unsigned short* __restrict__ elist_t,
    const int* __restrict__ cnt_s, const unsigned short* __restrict__ elist_s,
    const float* __restrict__ ss1, const float* __restrict__ ss2,
    const float* __restrict__ tt1, const float* __restrict__ tt2,
    const unsigned short* __restrict__ s_bf, const unsigned short* __restrict__ t_bf,
    float* __restrict__ h_st, float* __restrict__ h_ts)
{
    const int b     = blockIdx.x;
    const int slice = b & 7;            // = XCD id (round-robin dispatch)
    const int dir   = slice >> 2;
    const int h     = slice & 3;
    const int idx   = b >> 3;           // 0..255 within slice
    const int qg    = threadIdx.x >> 4; // quad id in block, 0..15
    const int l15   = threadIdx.x & 15;
    const int coff  = h * 64 + l15 * 4; // column within table row

    const int*            cnt   = dir ? cnt_s   : cnt_t;
    const unsigned short* list  = dir ? elist_s : elist_t;
    const unsigned short* table = dir ? t_bf    : s_bf;
    const float*          nsc   = dir ? ss2     : tt1;
    const float*          esc   = dir ? tt2     : ss1;
    float*                outp  = dir ? h_st    : h_ts;

    const float* esch = esc + h;

    const int nstart = (idx * N_NODES) >> 8;
    const int nend   = ((idx + 1) * N_NODES) >> 8;

    for (int n = nstart + qg; n < nend; n += 16) {
        const float base = nsc[n * HEADS + h];
        int deg = cnt[n];
        if (deg > ELL_CAP) deg = ELL_CAP;
        const unsigned short* lp = list + n * ELL_CAP;

        float4 acc = make_float4(0.f, 0.f, 0.f, 0.f);
        float den = 0.f;

        int p = 0;
        for (; p + 3 < deg; p += 4) {   // 4 independent gather chains
            int m0 = lp[p],     m1 = lp[p + 1];
            int m2 = lp[p + 2], m3 = lp[p + 3];
            float e0 = esch[m0 * HEADS], e1 = esch[m1 * HEADS];
            float e2 = esch[m2 * HEADS], e3 = esch[m3 * HEADS];
            ushort4 r0 = *(const ushort4*)(table + (size_t)m0 * NCOL + coff);
            ushort4 r1 = *(const ushort4*)(table + (size_t)m1 * NCOL + coff);
            ushort4 r2 = *(const ushort4*)(table + (size_t)m2 * NCOL + coff);
            ushort4 r3 = *(const ushort4*)(table + (size_t)m3 * NCOL + coff);
            float w0 = __expf(lrelu(e0 + base));
            float w1 = __expf(lrelu(e1 + base));
            float w2 = __expf(lrelu(e2 + base));
            float w3 = __expf(lrelu(e3 + base));
            den += (w0 + w1) + (w2 + w3);
            acc.x += (w0 * bf2f(r0.x) + w1 * bf2f(r1.x)) + (w2 * bf2f(r2.x) + w3 * bf2f(r3.x));
            acc.y += (w0 * bf2f(r0.y) + w1 * bf2f(r1.y)) + (w2 * bf2f(r2.y) + w3 * bf2f(r3.y));
            acc.z += (w0 * bf2f(r0.z) + w1 * bf2f(r1.z)) + (w2 * bf2f(r2.z) + w3 * bf2f(r3.z));
            acc.w += (w0 * bf2f(r0.w) + w1 * bf2f(r1.w)) + (w2 * bf2f(r2.w) + w3 * bf2f(r3.w));
        }
        for (; p < deg; ++p) {
            int m0 = lp[p];
            float w0 = __expf(lrelu(esch[m0 * HEADS] + base));
            ushort4 r0 = *(const ushort4*)(table + (size_t)m0 * NCOL + coff);
            den += w0;
            acc.x += w0 * bf2f(r0.x);
            acc.y += w0 * bf2f(r0.y);
            acc.z += w0 * bf2f(r0.z);
            acc.w += w0 * bf2f(r0.w);
        }

        if (den == 0.f) den = 1.f;
        float inv = 1.f / den;
        float4 r;
        r.x = acc.x * inv; r.y = acc.y * inv;
        r.z = acc.z * inv; r.w = acc.w * inv;
        r.x = (r.x > 0.f) ? r.x : expm1f(r.x);
        r.y = (r.y > 0.f) ? r.y : expm1f(r.y);
        r.z = (r.z > 0.f) ? r.z : expm1f(r.z);
        r.w = (r.w > 0.f) ? r.w : expm1f(r.w);
        *(float4*)(outp + (size_t)n * NCOL + coff) = r;
    }
}

extern "C" void kernel_launch(void* const* d_in, const int* in_sizes, int n_in,
                              void* d_out, int out_size, void* d_ws, size_t ws_size,
                              hipStream_t stream)
{
    const float* input1 = (const float*)d_in[0];
    const float* input2 = (const float*)d_in[1];
    const float* Ws     = (const float*)d_in[2];
    const float* Wt     = (const float*)d_in[3];
    const float* a1     = (const float*)d_in[4];
    const float* a2     = (const float*)d_in[5];
    const int*   tgt    = (const int*)d_in[6];   // tgt_idx precedes src_idx
    const int*   src    = (const int*)d_in[7];

    float* out  = (float*)d_out;
    float* h_st = out;                            // [N, 256]
    float* h_ts = out + (size_t)N_NODES * NCOL;   // [N, 256]

    // workspace layout (~27.3 MB)
    unsigned short* s_bf = (unsigned short*)d_ws;             // 5,120,000 bf16
    unsigned short* t_bf = s_bf + (size_t)N_NODES * NCOL;     // 5,120,000 bf16
    unsigned short* Wsb  = t_bf + (size_t)N_NODES * NCOL;     // 65,536 bf16
    unsigned short* Wtb  = Wsb + 256 * 256;                   // 65,536 bf16
    float* ss1  = (float*)(Wtb + 256 * 256);                  // 80,000 f each
    float* ss2  = ss1 + N_NODES * HEADS;
    float* tt1  = ss2 + N_NODES * HEADS;
    float* tt2  = tt1 + N_NODES * HEADS;
    int*   cnt_t = (int*)(tt2 + N_NODES * HEADS);             // 20000
    int*   cnt_s = cnt_t + N_NODES;                           // 20000
    unsigned short* elist_t = (unsigned short*)(cnt_s + N_NODES);   // 20000*64 us
    unsigned short* elist_s = elist_t + (size_t)N_NODES * ELL_CAP;  // 20000*64 us

    // dispatch 1: W convert + counter zeroing
    prep_w_kernel<<<64, 256, 0, stream>>>(Ws, Wt, Wsb, Wtb, cnt_t);

    // dispatch 2: standalone ELL scatter
    scatter_kernel<<<SCAT_BLOCKS, 256, 0, stream>>>(src, tgt, cnt_t, cnt_s,
                                                    elist_t, elist_s);

    // dispatch 3: half-W-resident GEMM + fused dots
    dim3 ggrid(GEMM_GB * 2, 2);
    gemm_wres_kernel<<<ggrid, 512, 0, stream>>>(input1, Wsb, input2, Wtb,
                                                s_bf, t_bf, a1, a2,
                                                ss1, ss2, tt1, tt2);

    // dispatch 4: XCD-sliced quad-per-node aggregation
    agg_kernel<<<AGG_BLOCKS, 256, 0, stream>>>(cnt_t, elist_t, cnt_s, elist_s,
                                               ss1, ss2, tt1, tt2, s_bf, t_bf, h_st, h_ts);
}

// Round 5
// 184.525 us; speedup vs baseline: 1.1877x; 1.1139x over previous
//
#include <hip/hip_runtime.h>
#include <math.h>

#define N_NODES 20000
#define N_EDGES 320000
#define IN_F 256
#define OUT_F 64
#define HEADS 4
#define NCOL 256            // HEADS*OUT_F
#define LRELU_ALPHA 0.1f
#define ELL_CAP 64          // max degree capacity; P(overflow) < 1e-13

#define SCAT_X 313                         // scatter blocks per y (512 thr, 1 edge/thread)
#define GEMM_GB 157                        // ceil(1250 row-groups / 8 waves)

typedef __attribute__((ext_vector_type(8))) short short8;
typedef __attribute__((ext_vector_type(4))) float floatx4;

__device__ __forceinline__ float lrelu(float x) {
    return x > 0.f ? x : LRELU_ALPHA * x;
}
__device__ __forceinline__ unsigned short f2bf(float f) {   // RNE f32->bf16
    unsigned int u = __float_as_uint(f);
    u = (u + 0x7FFF + ((u >> 16) & 1)) >> 16;
    return (unsigned short)u;
}
__device__ __forceinline__ float bf2f(unsigned short u) {
    return __uint_as_float(((unsigned int)u) << 16);
}

// ---------------------------------------------------------------------------
// prep_w (64 blocks x 256): W[h][k][j] f32 -> Wb[c][k] bf16 (c=h*64+j,
// k contiguous) AND zero the 2*N_NODES ELL counters.  [verified r0-r3]
// ---------------------------------------------------------------------------
__global__ __launch_bounds__(256) void prep_w_kernel(
    const float* __restrict__ Ws, const float* __restrict__ Wt,
    unsigned short* __restrict__ Wsb, unsigned short* __restrict__ Wtb,
    int* __restrict__ cnt)   // cnt_t followed by cnt_s
{
    const int gid = blockIdx.x * 256 + threadIdx.x;   // [0, 16384)

    for (int i = gid; i < 2 * N_NODES; i += 16384) cnt[i] = 0;

    const int mat = gid >> 13;
    const int r   = gid & 8191;
    const int kc  = r >> 8;          // 0..31 (k-octet)
    const int c   = r & 255;
    const float* W    = mat ? Wt : Ws;
    unsigned short* O = mat ? Wtb : Wsb;
    const int h = c >> 6, j = c & 63;
    const int k0 = kc * 8;
    unsigned short v[8] __attribute__((aligned(16)));
#pragma unroll
    for (int i = 0; i < 8; ++i)
        v[i] = f2bf(W[(size_t)h * (IN_F * OUT_F) + (size_t)(k0 + i) * OUT_F + j]);
    *(uint4*)(O + (size_t)c * IN_F + k0) = *(const uint4*)v;
}

// ---------------------------------------------------------------------------
// hybrid: scatter specialists (x < SCAT_X, 1 edge/thread) + half-W-resident
// GEMM + fused dots (x >= SCAT_X; byte-identical to round-3's verified gemm).
// Merging removes one inter-dispatch gap.
// ---------------------------------------------------------------------------
__global__ __launch_bounds__(512, 4) void hybrid_kernel(
    const float* __restrict__ A0, const unsigned short* __restrict__ Wb0,
    const float* __restrict__ A1, const unsigned short* __restrict__ Wb1,
    unsigned short* __restrict__ C0, unsigned short* __restrict__ C1,
    const float* __restrict__ a1, const float* __restrict__ a2,
    float* __restrict__ ss1, float* __restrict__ ss2,
    float* __restrict__ tt1, float* __restrict__ tt2,
    const int* __restrict__ src, const int* __restrict__ tgt,
    int* __restrict__ cnt_t, int* __restrict__ cnt_s,
    unsigned short* __restrict__ elist_t, unsigned short* __restrict__ elist_s)
{
    const int tid = threadIdx.x;

    __shared__ __align__(16) unsigned short Bl[128][264];   // 67,584 B

    if (blockIdx.x < SCAT_X) {
        // ---- scatter: one edge per thread ----
        const int e = ((int)blockIdx.y * SCAT_X + (int)blockIdx.x) * 512 + tid;
        if (e < N_EDGES) {
            const int s = src[e], t = tgt[e];
            const int p = atomicAdd(&cnt_t[t], 1);
            const int q = atomicAdd(&cnt_s[s], 1);
            if (p < ELL_CAP) elist_t[t * ELL_CAP + p] = (unsigned short)s;
            if (q < ELL_CAP) elist_s[s * ELL_CAP + q] = (unsigned short)t;
        }
        return;
    }

    // ---- GEMM + fused dots (round-3 verified) ----
    const int gx   = blockIdx.x - SCAT_X;
    const int half = gx & 1;
    const int gb   = gx >> 1;             // 0..156
    const float* A           = (blockIdx.y == 0) ? A0 : A1;
    const unsigned short* Wb = (blockIdx.y == 0) ? Wb0 : Wb1;
    unsigned short* C        = (blockIdx.y == 0) ? C0 : C1;

    for (int i = tid; i < 4096; i += 512) {
        const int n  = i >> 5;            // 0..127
        const int kc = (i & 31) << 3;     // k-offset in shorts
        *(uint4*)&Bl[n][kc] = *(const uint4*)(Wb + (size_t)(half * 128 + n) * IN_F + kc);
    }
    __syncthreads();

    const int lane = tid & 63;
    const int w    = tid >> 6;            // wave 0..7
    const int quad = lane >> 4;
    const int l15  = lane & 15;
    const int g    = gb * 8 + w;          // row group 0..1255
    if (g >= 1250) return;

    const float* arow = A + (size_t)(g * 16 + l15) * IN_F + quad * 8;

    // batch 1: kk = 0..3
    float4 ua[8];
#pragma unroll
    for (int kk = 0; kk < 4; ++kk) {
        ua[2 * kk]     = *(const float4*)(arow + kk * 32);
        ua[2 * kk + 1] = *(const float4*)(arow + kk * 32 + 4);
    }
    short8 af[4];
#pragma unroll
    for (int kk = 0; kk < 4; ++kk) {
        short8 t;
        t[0] = (short)f2bf(ua[2 * kk].x);     t[1] = (short)f2bf(ua[2 * kk].y);
        t[2] = (short)f2bf(ua[2 * kk].z);     t[3] = (short)f2bf(ua[2 * kk].w);
        t[4] = (short)f2bf(ua[2 * kk + 1].x); t[5] = (short)f2bf(ua[2 * kk + 1].y);
        t[6] = (short)f2bf(ua[2 * kk + 1].z); t[7] = (short)f2bf(ua[2 * kk + 1].w);
        af[kk] = t;
    }

    // batch 2 loads fly under batch-1 MFMAs
    float4 ub[8];
#pragma unroll
    for (int kk = 0; kk < 4; ++kk) {
        ub[2 * kk]     = *(const float4*)(arow + (kk + 4) * 32);
        ub[2 * kk + 1] = *(const float4*)(arow + (kk + 4) * 32 + 4);
    }

    floatx4 acc[8];
#pragma unroll
    for (int c = 0; c < 8; ++c) acc[c] = (floatx4){0.f, 0.f, 0.f, 0.f};

#pragma unroll
    for (int kk = 0; kk < 4; ++kk) {
#pragma unroll
        for (int c = 0; c < 8; ++c) {
            short8 bfrag = *(const short8*)&Bl[c * 16 + l15][kk * 32 + quad * 8];
            acc[c] = __builtin_amdgcn_mfma_f32_16x16x32_bf16(af[kk], bfrag, acc[c], 0, 0, 0);
        }
    }

#pragma unroll
    for (int kk = 0; kk < 4; ++kk) {
        short8 t;
        t[0] = (short)f2bf(ub[2 * kk].x);     t[1] = (short)f2bf(ub[2 * kk].y);
        t[2] = (short)f2bf(ub[2 * kk].z);     t[3] = (short)f2bf(ub[2 * kk].w);
        t[4] = (short)f2bf(ub[2 * kk + 1].x); t[5] = (short)f2bf(ub[2 * kk + 1].y);
        t[6] = (short)f2bf(ub[2 * kk + 1].z); t[7] = (short)f2bf(ub[2 * kk + 1].w);
        af[kk] = t;
    }
#pragma unroll
    for (int kk = 0; kk < 4; ++kk) {
#pragma unroll
        for (int c = 0; c < 8; ++c) {
            short8 bfrag = *(const short8*)&Bl[c * 16 + l15][(kk + 4) * 32 + quad * 8];
            acc[c] = __builtin_amdgcn_mfma_f32_16x16x32_bf16(af[kk], bfrag, acc[c], 0, 0, 0);
        }
    }

    // ---- C write (bf16) ----
#pragma unroll
    for (int c = 0; c < 8; ++c) {
        const int col = half * 128 + c * 16 + l15;
#pragma unroll
        for (int r = 0; r < 4; ++r) {
            const int m = g * 16 + quad * 4 + r;
            C[(size_t)m * NCOL + col] = f2bf(acc[c][r]);
        }
    }

    // ---- fused dots for the 2 heads in this half ----
    const int off_aj = (blockIdx.y == 0) ? 0 : 64;
    float* o1 = (blockIdx.y == 0) ? ss1 : tt1;
    float* o2 = (blockIdx.y == 0) ? ss2 : tt2;

    float p1[2][4] = {{0.f,0.f,0.f,0.f},{0.f,0.f,0.f,0.f}};
    float p2[2][4] = {{0.f,0.f,0.f,0.f},{0.f,0.f,0.f,0.f}};
#pragma unroll
    for (int c = 0; c < 8; ++c) {
        const int hl = c >> 2;                       // local head 0..1
        const int hh = half * 2 + hl;
        const int jj = (c & 3) * 16 + l15;
        const float w1 = a1[hh * 128 + off_aj + jj];
        const float w2 = a2[hh * 128 + off_aj + jj];
#pragma unroll
        for (int r = 0; r < 4; ++r) {
            p1[hl][r] += acc[c][r] * w1;
            p2[hl][r] += acc[c][r] * w2;
        }
    }
#pragma unroll
    for (int m = 1; m < 16; m <<= 1) {
#pragma unroll
        for (int hl = 0; hl < 2; ++hl)
#pragma unroll
            for (int r = 0; r < 4; ++r) {
                p1[hl][r] += __shfl_xor(p1[hl][r], m, 64);
                p2[hl][r] += __shfl_xor(p2[hl][r], m, 64);
            }
    }
    if (l15 == 0) {
#pragma unroll
        for (int r = 0; r < 4; ++r) {
            const int m = g * 16 + quad * 4 + r;
#pragma unroll
            for (int hl = 0; hl < 2; ++hl) {
                const int hh = half * 2 + hl;
                o1[m * HEADS + hh] = p1[hl][r];
                o2[m * HEADS + hh] = p2[hl][r];
            }
        }
    }
}

// ---------------------------------------------------------------------------
// agg: round-1 verified body (49 us, wave-per-node, 4-edge unroll, ushort
// ELL, full 256-col row per wave, 1 exp per edge-head). ONLY change: 1D grid
// with dir = blockIdx.x & 1, so under round-robin block->XCD dispatch each
// direction's 10.2 MB table is cached by 4 XCDs instead of replicated on 8.
// ---------------------------------------------------------------------------
__global__ __launch_bounds__(256) void agg_kernel(
    const int* __restrict__ cnt_t, const unsigned short* __restrict__ elist_t,
    const int* __restrict__ cnt_s, const unsigned short* __restrict__ elist_s,
    const float* __restrict__ ss1, const float* __restrict__ ss2,
    const float* __restrict__ tt1, const float* __restrict__ tt2,
    const unsigned short* __restrict__ s_bf, const unsigned short* __restrict__ t_bf,
    float* __restrict__ h_st, float* __restrict__ h_ts)
{
    const int b    = blockIdx.x;            // 0..9999
    const int dir  = b & 1;                 // = XCD parity
    const int wave = threadIdx.x >> 6;
    const int lane = threadIdx.x & 63;
    const int n    = (b >> 1) * 4 + wave;   // 5000*4 == 20000
    const int h    = lane >> 4;
    const int coff = lane * 4;

    const int*            cnt   = dir ? cnt_s   : cnt_t;
    const unsigned short* list  = dir ? elist_s : elist_t;
    const unsigned short* table = dir ? t_bf    : s_bf;
    const float*          nsc   = dir ? ss2     : tt1;
    const float*          esc   = dir ? tt2     : ss1;
    float*                outp  = dir ? h_st    : h_ts;

    const float base = nsc[n * HEADS + h];
    int deg = cnt[n];
    if (deg > ELL_CAP) deg = ELL_CAP;
    const int b0 = n * ELL_CAP, b1 = b0 + deg;

    float4 acc = make_float4(0.f, 0.f, 0.f, 0.f);
    float den = 0.f;

    int p = b0;
    for (; p + 3 < b1; p += 4) {
        int m0 = list[p],     m1 = list[p + 1];
        int m2 = list[p + 2], m3 = list[p + 3];
        float e0 = esc[m0 * HEADS + h], e1 = esc[m1 * HEADS + h];
        float e2 = esc[m2 * HEADS + h], e3 = esc[m3 * HEADS + h];
        ushort4 r0 = *(const ushort4*)(table + (size_t)m0 * NCOL + coff);
        ushort4 r1 = *(const ushort4*)(table + (size_t)m1 * NCOL + coff);
        ushort4 r2 = *(const ushort4*)(table + (size_t)m2 * NCOL + coff);
        ushort4 r3 = *(const ushort4*)(table + (size_t)m3 * NCOL + coff);
        float w0 = __expf(lrelu(e0 + base));
        float w1 = __expf(lrelu(e1 + base));
        float w2 = __expf(lrelu(e2 + base));
        float w3 = __expf(lrelu(e3 + base));
        den += (w0 + w1) + (w2 + w3);
        acc.x += (w0 * bf2f(r0.x) + w1 * bf2f(r1.x)) + (w2 * bf2f(r2.x) + w3 * bf2f(r3.x));
        acc.y += (w0 * bf2f(r0.y) + w1 * bf2f(r1.y)) + (w2 * bf2f(r2.y) + w3 * bf2f(r3.y));
        acc.z += (w0 * bf2f(r0.z) + w1 * bf2f(r1.z)) + (w2 * bf2f(r2.z) + w3 * bf2f(r3.z));
        acc.w += (w0 * bf2f(r0.w) + w1 * bf2f(r1.w)) + (w2 * bf2f(r2.w) + w3 * bf2f(r3.w));
    }
    for (; p < b1; ++p) {
        int m0 = list[p];
        float w0 = __expf(lrelu(esc[m0 * HEADS + h] + base));
        ushort4 r0 = *(const ushort4*)(table + (size_t)m0 * NCOL + coff);
        den += w0;
        acc.x += w0 * bf2f(r0.x);
        acc.y += w0 * bf2f(r0.y);
        acc.z += w0 * bf2f(r0.z);
        acc.w += w0 * bf2f(r0.w);
    }

    if (den == 0.f) den = 1.f;
    float inv = 1.f / den;
    float4 r;
    r.x = acc.x * inv; r.y = acc.y * inv; r.z = acc.z * inv; r.w = acc.w * inv;
    r.x = (r.x > 0.f) ? r.x : expm1f(r.x);
    r.y = (r.y > 0.f) ? r.y : expm1f(r.y);
    r.z = (r.z > 0.f) ? r.z : expm1f(r.z);
    r.w = (r.w > 0.f) ? r.w : expm1f(r.w);
    *(float4*)(outp + (size_t)n * NCOL + coff) = r;
}

extern "C" void kernel_launch(void* const* d_in, const int* in_sizes, int n_in,
                              void* d_out, int out_size, void* d_ws, size_t ws_size,
                              hipStream_t stream)
{
    const float* input1 = (const float*)d_in[0];
    const float* input2 = (const float*)d_in[1];
    const float* Ws     = (const float*)d_in[2];
    const float* Wt     = (const float*)d_in[3];
    const float* a1     = (const float*)d_in[4];
    const float* a2     = (const float*)d_in[5];
    const int*   tgt    = (const int*)d_in[6];   // tgt_idx precedes src_idx
    const int*   src    = (const int*)d_in[7];

    float* out  = (float*)d_out;
    float* h_st = out;                            // [N, 256]
    float* h_ts = out + (size_t)N_NODES * NCOL;   // [N, 256]

    // workspace layout (~27.3 MB)
    unsigned short* s_bf = (unsigned short*)d_ws;             // 5,120,000 bf16
    unsigned short* t_bf = s_bf + (size_t)N_NODES * NCOL;     // 5,120,000 bf16
    unsigned short* Wsb  = t_bf + (size_t)N_NODES * NCOL;     // 65,536 bf16
    unsigned short* Wtb  = Wsb + 256 * 256;                   // 65,536 bf16
    float* ss1  = (float*)(Wtb + 256 * 256);                  // 80,000 f each
    float* ss2  = ss1 + N_NODES * HEADS;
    float* tt1  = ss2 + N_NODES * HEADS;
    float* tt2  = tt1 + N_NODES * HEADS;
    int*   cnt_t = (int*)(tt2 + N_NODES * HEADS);             // 20000
    int*   cnt_s = cnt_t + N_NODES;                           // 20000
    unsigned short* elist_t = (unsigned short*)(cnt_s + N_NODES);   // 20000*64 us
    unsigned short* elist_s = elist_t + (size_t)N_NODES * ELL_CAP;  // 20000*64 us

    // dispatch 1: W convert + counter zeroing
    prep_w_kernel<<<64, 256, 0, stream>>>(Ws, Wt, Wsb, Wtb, cnt_t);

    // dispatch 2: hybrid scatter + GEMM + fused dots
    dim3 ggrid(SCAT_X + GEMM_GB * 2, 2);
    hybrid_kernel<<<ggrid, 512, 0, stream>>>(input1, Wsb, input2, Wtb,
                                             s_bf, t_bf, a1, a2,
                                             ss1, ss2, tt1, tt2,
                                             src, tgt, cnt_t, cnt_s,
                                             elist_t, elist_s);

    // dispatch 3: dir-parity XCD-mapped aggregation (round-1 body)
    agg_kernel<<<10000, 256, 0, stream>>>(cnt_t, elist_t, cnt_s, elist_s,
                                          ss1, ss2, tt1, tt2, s_bf, t_bf, h_st, h_ts);
}